// Round 16
// baseline (947.749 us; speedup 1.0000x reference)
//
#include <hip/hip_runtime.h>
#include <hip/hip_bf16.h>

#define TSEQ 2048
#define TBZ  32
#define TDIM 1024
#define NLS  8

typedef __attribute__((ext_vector_type(8))) short bf16x8;
typedef __attribute__((ext_vector_type(4))) float f32x4;

__device__ inline unsigned int pk2(float lo, float hi) {
    __hip_bfloat162 h = __float22bfloat162_rn(make_float2(lo, hi)); // v_cvt_pk_bf16_f32
    return *reinterpret_cast<const unsigned int*>(&h);
}

__device__ inline void gload_lds16(const void* g, void* l) {
    __builtin_amdgcn_global_load_lds(
        (const __attribute__((address_space(1))) unsigned int*)g,
        (__attribute__((address_space(3))) unsigned int*)l,
        16, 0, 0);
}

// ---------- dispatch 1: W conv + FIRST-needed A tiles {0,4} + flag zero ----
// (r13/r14-verified.) Blocks [0,256): W f32->bf16. Blocks [256,512): tiles
// {0,4} x 32 b x 4 quarter-blocks of 64 rows. Block 512: zero 256 flags.
__global__ __launch_bounds__(256) void conv_pre(
    const float* __restrict__ x, const int* __restrict__ lang_ids,
    const float* __restrict__ W,
    unsigned short* __restrict__ xb, unsigned short* __restrict__ wb,
    int* __restrict__ flags)
{
    const int bid = blockIdx.x;
    if (bid == 512) {
        if (threadIdx.x < 256) flags[threadIdx.x] = 0;
        return;
    }
    if (bid < 256) {                               // W part
        const int total = NLS * TDIM * TDIM / 8;
        for (int i = bid * 256 + threadIdx.x; i < total; i += 256 * 256) {
            const float* src = W + (long)i * 8;
            f32x4 v0 = *(const f32x4*)(src);
            f32x4 v1 = *(const f32x4*)(src + 4);
            uint4 o;
            o.x = pk2(v0.x, v0.y); o.y = pk2(v0.z, v0.w);
            o.z = pk2(v1.x, v1.y); o.w = pk2(v1.z, v1.w);
            *(uint4*)(wb + (long)i * 8) = o;
        }
        return;
    }
    // first tiles: i in [0,256): chunk c=i>>2 (b=c>>1, mt=(c&1)*4), quarter q
    const int i  = bid - 256;
    const int c  = i >> 2;
    const int q  = i & 3;
    const int b  = c >> 1;
    const int gid = 8 - lang_ids[b];
    if (!(gid >= 1 && gid <= 8)) return;
    const int srow0 = (c & 1) * 4 * 256 + q * 64;
    for (int r = 0; r < 64; ++r) {
        const int s = srow0 + r;
        const float* sp = x + ((long)s * TBZ + b) * TDIM + threadIdx.x * 4;
        f32x4 v = *(const f32x4*)sp;
        uint2 o; o.x = pk2(v.x, v.y); o.y = pk2(v.z, v.w);
        *(uint2*)(xb + ((long)b * TSEQ + s) * TDIM + threadIdx.x * 4) = o;
    }
}

// ---------- dispatch 2: r15 GEMM (waves 0-7) + converter waves (8-9) -------
// GEMM core byte-identical to r10/r15 (158 us, verified 6x). NEW: block is
// 640 threads; waves 8-9 are CONVERTER waves with their OWN per-wave vmcnt
// chains (r14's failure mechanism -- shared in-order vmcnt -- is absent).
// Conv waves convert this block's nt-quarter (64 rows, cols cw*512..+511)
// of m-tile strip*4+mtl+1 during its 0-1 (2 rows per barrier-gap), then
// VMC(0) + agent-RELEASE fetch_add at it 2. GEMM waves spin (relaxed +
// sleep, then agent-ACQUIRE) for flag==4 at top of it==7, before the first
// cross-tile stage (it7-P2).
// Barrier count matched EXACTLY: both roles execute 1 (prologue) + 32 its
// x 16 = 513 s_barriers; inactive-b blocks exit (all 10 waves) before any.
// Deadlock-free by induction: release(mtl+1)@it2 precedes spin(mtl+1)@it7
// in every block's own barrier sequence; grid 256 = 1 block/CU all-resident.

#define BAR __builtin_amdgcn_s_barrier()
#define SB0 __builtin_amdgcn_sched_barrier(0)
#define VMC(n) asm volatile("s_waitcnt vmcnt(" #n ")" ::: "memory")
#define KAo(kv) (((kv) & 1023) + (((kv) >> 10) << 18))
#define KBo(kv) ((kv) & 1023)

__global__ __launch_bounds__(640) void mapper_gemm8p(
    const float* __restrict__ x,                // [s][b][d] f32
    unsigned short* xb,                          // [b][s][d] bf16 (read+write)
    const int* __restrict__ lang_ids,
    const unsigned short* __restrict__ wb,      // [e][out][in] bf16
    const float* __restrict__ bias,
    int* flags,
    float* __restrict__ out)
{
    // XCD-chunked bijective swizzle: 256 = 8 * 32; nt fastest. The 4
    // nt-peers of a (b,strip) share p%8 -> same-XCD producer/consumer.
    const int p  = blockIdx.x;
    const int l  = (p & 7) * 32 + (p >> 3);
    const int b  = l >> 3;
    const int strip = (l >> 2) & 1;             // 4 m-tiles per strip
    const int nt = l & 3;
    const int s0 = strip * 1024;
    const int e0 = nt * 256;
    const int tid = threadIdx.x;

    const int gid = 8 - lang_ids[b];
    if (!(gid >= 1 && gid <= 8)) {
        // passthrough: out[s0..s0+1024][b][e0..e0+256] = x[...]; all 640 thr
        const f32x4* xs = (const f32x4*)x;
        f32x4*       os = (f32x4*)out;
        const int rs4 = TBZ * TDIM / 4;
        for (int i = tid; i < 1024 * 256 / 4; i += 640) {
            int r = i >> 6;
            int c = i & 63;
            long idx = (long)(s0 + r) * rs4 + b * (TDIM / 4) + (e0 >> 2) + c;
            os[idx] = xs[idx];
        }
        return;
    }
    const int eb = gid - 1;

    __shared__ uint4 ldsbuf[131072 / 16];
    char* ldsc = (char*)ldsbuf;

    const int lane = tid & 63;
    const int wave = tid >> 6;
    const int flbase = (b * 2 + strip) * 4;

    // ---------------- converter role: waves 8-9 ----------------
    if (wave >= 8) {
        const int cw = wave - 8;                // 0,1 -> col halves
        BAR;                                    // matches GEMM prologue BAR
        #pragma unroll 1
        for (int mtl = 0; mtl < 4; ++mtl) {
            #pragma unroll 1
            for (int it = 0; it < 8; ++it) {
                #pragma unroll 1
                for (int k = 0; k < 16; ++k) {
                    if (mtl < 3 && it < 2) {
                        // rows of GLOBAL m-tile strip*4+mtl+1 (r14-verified
                        // coverage): quarter base + it*32 + k*2 + j
                        const int mt = strip * 4 + mtl + 1;
                        const int r0 = mt * 256 + nt * 64 + it * 32 + k * 2;
                        #pragma unroll
                        for (int j = 0; j < 2; ++j) {
                            const int s = r0 + j;
                            const float* sp = x + ((long)s * TBZ + b) * TDIM
                                                + cw * 512 + lane * 8;
                            f32x4 v0 = *(const f32x4*)sp;
                            f32x4 v1 = *(const f32x4*)(sp + 4);
                            uint4 o;
                            o.x = pk2(v0.x, v0.y); o.y = pk2(v0.z, v0.w);
                            o.z = pk2(v1.x, v1.y); o.w = pk2(v1.z, v1.w);
                            *(uint4*)(xb + ((long)b * TSEQ + s) * TDIM
                                         + cw * 512 + lane * 8) = o;
                        }
                    }
                    if (mtl < 3 && it == 2 && k == 0) { VMC(0); }
                    BAR;
                    if (mtl < 3 && it == 2 && k == 0 && cw == 0 && lane == 0)
                        __hip_atomic_fetch_add(&flags[flbase + mtl + 1], 1,
                                               __ATOMIC_RELEASE,
                                               __HIP_MEMORY_SCOPE_AGENT);
                }
            }
        }
        return;
    }

    // ---------------- GEMM role: waves 0-7 (r15 byte-identical core) -------
    const int wr   = wave >> 2;
    const int wc   = wave & 3;
    const int fr   = lane & 15;
    const int fq   = lane >> 4;
    const int fr7  = fr & 7;

    const unsigned short* Aab = xb + (long)b  * TSEQ * TDIM + (long)s0 * TDIM;
    const unsigned short* __restrict__ Bbb = wb + (long)eb * TDIM * TDIM + (long)e0 * TDIM;

    const int L    = lane;
    const int lch8 = ((L & 7) ^ (L >> 3)) * 8;   // pre-inverse-swizzled global chunk
    const int ldA0 = wave * 2048 + L * 16;
    const unsigned short* aG[2][2];
    const unsigned short* bG[2][2];
    #pragma unroll
    for (int j = 0; j < 2; ++j) {
        const int rr = wave * 16 + j * 8 + (L >> 3);
        #pragma unroll
        for (int mh = 0; mh < 2; ++mh)
            aG[j][mh] = Aab + ((rr >> 6) * 128 + mh * 64 + (rr & 63)) * TDIM + lch8;
        #pragma unroll
        for (int nh = 0; nh < 2; ++nh)
            bG[j][nh] = Bbb + ((rr >> 5) * 64 + nh * 32 + (rr & 31)) * TDIM + lch8;
    }

#define STAGE_A(slot, mh, kofs) do { \
    gload_lds16(aG[0][mh] + (kofs), ldsc + (slot)*32768 + (mh)*16384 + ldA0); \
    gload_lds16(aG[1][mh] + (kofs), ldsc + (slot)*32768 + (mh)*16384 + ldA0 + 1024); \
} while (0)
#define STAGE_B(slot, nh, kofs) do { \
    gload_lds16(bG[0][nh] + (kofs), ldsc + 65536 + (slot)*32768 + (nh)*16384 + ldA0); \
    gload_lds16(bG[1][nh] + (kofs), ldsc + 65536 + (slot)*32768 + (nh)*16384 + ldA0 + 1024); \
} while (0)
#define RD_A(slot, mh) do { \
    _Pragma("unroll") for (int ml = 0; ml < 4; ++ml) { \
        const int rr = wr * 64 + ml * 16 + fr; \
        _Pragma("unroll") for (int kk = 0; kk < 2; ++kk) \
            af[ml][kk] = *(const bf16x8*)(ldsc + (slot)*32768 + (mh)*16384 + rr*128 + (((kk*4+fq) ^ fr7) << 4)); \
    } } while (0)
#define RD_B(slot, nh, br) do { \
    _Pragma("unroll") for (int nl = 0; nl < 2; ++nl) { \
        const int rr = wc * 32 + nl * 16 + fr; \
        _Pragma("unroll") for (int kk = 0; kk < 2; ++kk) \
            br[nl][kk] = *(const bf16x8*)(ldsc + 65536 + (slot)*32768 + (nh)*16384 + rr*128 + (((kk*4+fq) ^ fr7) << 4)); \
    } } while (0)
// Swapped operands (C^T): col=lane&15 -> s_local, row=(lane>>4)*4+j -> e_local.
#define MM(mh, nh, br) do { \
    __builtin_amdgcn_s_setprio(1); \
    _Pragma("unroll") for (int ml = 0; ml < 4; ++ml) \
    _Pragma("unroll") for (int nl = 0; nl < 2; ++nl) \
    _Pragma("unroll") for (int kk = 0; kk < 2; ++kk) \
        acc[(mh)*4+ml][(nh)*2+nl] = __builtin_amdgcn_mfma_f32_16x16x32_bf16( \
            br[nl][kk], af[ml][kk], acc[(mh)*4+ml][(nh)*2+nl], 0, 0, 0); \
    __builtin_amdgcn_s_setprio(0); \
} while (0)

    f32x4 acc[8][4];
    #pragma unroll
    for (int m = 0; m < 8; ++m)
        #pragma unroll
        for (int n = 0; n < 4; ++n)
            acc[m][n] = (f32x4){0.f, 0.f, 0.f, 0.f};

    bf16x8 af[4][2], bf0[2][2], bf1[2][2];

    // prologue: tile0 all 4 halves + tile1 {Amh0,Bnh0,Bnh1} (tiles 0,4 were
    // converted by conv_pre; stream order guarantees visibility)
    STAGE_A(0, 0, 0);  STAGE_B(0, 0, 0);  STAGE_B(0, 1, 0);  STAGE_A(0, 1, 0);
    STAGE_A(1, 0, 64); STAGE_B(1, 0, 64); STAGE_B(1, 1, 64);
    VMC(6); BAR; SB0;

    const int cs  = lane & 15;          // s_local
    const int eqb = (lane >> 4) << 2;   // e_local base (4 consecutive)

    #pragma unroll 1
    for (int mtl = 0; mtl < 4; ++mtl) {
        #pragma unroll 1
        for (int it = 0; it < 8; ++it) {
            // consumer spin: next m-tile converted before it7-P2's stage
            if (it == 7 && mtl < 3) {
                if (lane == 0) {
                    while (__hip_atomic_load(&flags[flbase + mtl + 1],
                                             __ATOMIC_RELAXED,
                                             __HIP_MEMORY_SCOPE_AGENT) < 4)
                        __builtin_amdgcn_s_sleep(2);
                }
                __hip_atomic_load(&flags[flbase + mtl + 1],
                                  __ATOMIC_ACQUIRE, __HIP_MEMORY_SCOPE_AGENT);
                SB0;
            }
            const int kva = mtl * 1024 + it * 128;
            const int kb = kva + 64;
            const int kn = kva + 128;   // wraps into next m-tile after it=7
            const int km = kva + 192;
            // P1
            RD_A(0, 0); RD_B(0, 0, bf0); STAGE_A(1, 1, KAo(kb));
            BAR; SB0; MM(0, 0, bf0); BAR; SB0;
            // P2
            RD_B(0, 1, bf1); STAGE_A(0, 0, KAo(kn));
            BAR; SB0; MM(0, 1, bf1); BAR; SB0;
            // P3
            RD_A(0, 1); STAGE_B(0, 0, KBo(kn));
            BAR; SB0; MM(1, 0, bf0); BAR; SB0;
            // P4
            STAGE_B(0, 1, KBo(kn));
            BAR; SB0; MM(1, 1, bf1); VMC(6); BAR; SB0;
            // P5
            RD_A(1, 0); RD_B(1, 0, bf0); STAGE_A(0, 1, KAo(kn));
            BAR; SB0; MM(0, 0, bf0); BAR; SB0;
            // P6
            RD_B(1, 1, bf1); STAGE_A(1, 0, KAo(km));
            BAR; SB0; MM(0, 1, bf1); BAR; SB0;
            // P7
            RD_A(1, 1); STAGE_B(1, 0, KBo(km));
            BAR; SB0; MM(1, 0, bf0); BAR; SB0;
            // P8
            STAGE_B(1, 1, KBo(km));
            BAR; SB0; MM(1, 1, bf1); VMC(6); BAR; SB0;
        }

        // epilogue: 32 dwordx4 stores; drain overlaps the bridge prefetch
        const int sb = s0 + mtl * 256 + wr * 128;
        #pragma unroll
        for (int n = 0; n < 4; ++n) {
            const int e = e0 + wc * 64 + n * 16 + eqb;
            const f32x4 bv4 = *(const f32x4*)&bias[eb * TDIM + e];
            #pragma unroll
            for (int m = 0; m < 8; ++m) {
                const int s = sb + m * 16 + cs;
                *(f32x4*)&out[(long)s * (TBZ * TDIM) + b * TDIM + e] = acc[m][n] + bv4;
            }
        }
        #pragma unroll
        for (int m = 0; m < 8; ++m)
            #pragma unroll
            for (int n = 0; n < 4; ++n)
                acc[m][n] = (f32x4){0.f, 0.f, 0.f, 0.f};
    }
#undef STAGE_A
#undef STAGE_B
#undef RD_A
#undef RD_B
#undef MM
}

// ---------- fallback: round-1 fused kernel ----------
__device__ inline unsigned short f2bf(float f) {
    union { float f; unsigned int u; } v; v.f = f;
    unsigned int r = v.u + 0x7fffu + ((v.u >> 16) & 1u);
    return (unsigned short)(r >> 16);
}
constexpr int FLDS = 40;

__global__ __launch_bounds__(256) void mapper_fused(
    const float* __restrict__ x, const int* __restrict__ lang_ids,
    const float* __restrict__ W, const float* __restrict__ bias,
    float* __restrict__ out)
{
    const int bid = blockIdx.x;
    const int b   = bid >> 7;
    const int t   = bid & 127;
    const int mt  = t >> 3;
    const int nt  = t & 7;
    const int s0  = mt * 128;
    const int e0  = nt * 128;
    const int tid = threadIdx.x;

    const int gid = 8 - lang_ids[b];
    const bool active = (gid >= 1) && (gid <= 8);
    int eb = gid - 1; eb = eb < 0 ? 0 : (eb > 7 ? 7 : eb);

    if (!active) {
        const f32x4* xs = (const f32x4*)x;
        f32x4*       os = (f32x4*)out;
        const int rs4 = TBZ * TDIM / 4;
        for (int i = tid; i < 128 * 128 / 4; i += 256) {
            int r = i >> 5, c = i & 31;
            long idx = (long)(s0 + r) * rs4 + b * (TDIM / 4) + (e0 >> 2) + c;
            os[idx] = xs[idx];
        }
        return;
    }

    __shared__ unsigned short As[128 * FLDS];
    __shared__ unsigned short Bs[128 * FLDS];
    const float* __restrict__ Wb = W + (long)eb * TDIM * TDIM;

    const int lane = tid & 63;
    const int wave = tid >> 6;
    const int wrr  = wave >> 1;
    const int wcc  = wave & 1;

    f32x4 acc[4][4];
    #pragma unroll
    for (int m = 0; m < 4; ++m)
        #pragma unroll
        for (int n = 0; n < 4; ++n)
            acc[m][n] = (f32x4){0.f, 0.f, 0.f, 0.f};

    const int rg = tid >> 3;
    const int cg = tid & 7;
    const int fr = lane & 15;
    const int fo = (lane >> 4) * 8;

    for (int k0 = 0; k0 < TDIM; k0 += 32) {
        __syncthreads();
        #pragma unroll
        for (int pp = 0; pp < 4; ++pp) {
            const int r = rg + pp * 32;
            f32x4 av = *(const f32x4*)(x  + (long)(s0 + r) * (TBZ * TDIM) + b * TDIM + k0 + cg * 4);
            f32x4 bv = *(const f32x4*)(Wb + (long)(e0 + r) * TDIM + k0 + cg * 4);
            unsigned int alo = (unsigned)f2bf(av.x) | ((unsigned)f2bf(av.y) << 16);
            unsigned int ahi = (unsigned)f2bf(av.z) | ((unsigned)f2bf(av.w) << 16);
            unsigned int blo = (unsigned)f2bf(bv.x) | ((unsigned)f2bf(bv.y) << 16);
            unsigned int bhi = (unsigned)f2bf(bv.z) | ((unsigned)f2bf(bv.w) << 16);
            *(uint2*)&As[r * FLDS + cg * 4] = make_uint2(alo, ahi);
            *(uint2*)&Bs[r * FLDS + cg * 4] = make_uint2(blo, bhi);
        }
        __syncthreads();

        bf16x8 af2[4], bfm[4];
        #pragma unroll
        for (int m = 0; m < 4; ++m)
            af2[m] = *(const bf16x8*)&As[(wrr * 64 + m * 16 + fr) * FLDS + fo];
        #pragma unroll
        for (int n = 0; n < 4; ++n)
            bfm[n] = *(const bf16x8*)&Bs[(wcc * 64 + n * 16 + fr) * FLDS + fo];
        #pragma unroll
        for (int m = 0; m < 4; ++m)
            #pragma unroll
            for (int n = 0; n < 4; ++n)
                acc[m][n] = __builtin_amdgcn_mfma_f32_16x16x32_bf16(af2[m], bfm[n], acc[m][n], 0, 0, 0);
    }

    const int cr = lane >> 4;
    const int cc2 = lane & 15;
    #pragma unroll
    for (int n = 0; n < 4; ++n) {
        const int e  = e0 + wcc * 64 + n * 16 + cc2;
        const float bv = bias[eb * TDIM + e];
        #pragma unroll
        for (int m = 0; m < 4; ++m) {
            #pragma unroll
            for (int j = 0; j < 4; ++j) {
                const int s = s0 + wrr * 64 + m * 16 + cr * 4 + j;
                out[(long)s * (TBZ * TDIM) + b * TDIM + e] = acc[m][n][j] + bv;
            }
        }
    }
}

extern "C" void kernel_launch(void* const* d_in, const int* in_sizes, int n_in,
                              void* d_out, int out_size, void* d_ws, size_t ws_size,
                              hipStream_t stream) {
    const float* x        = (const float*)d_in[0];
    const int*   lang_ids = (const int*)d_in[1];
    const float* W        = (const float*)d_in[2];
    const float* bias     = (const float*)d_in[3];
    float*       out      = (float*)d_out;

    const size_t xbytes = (size_t)TSEQ * TBZ * TDIM * 2;   // 128 MiB
    const size_t wbytes = (size_t)NLS * TDIM * TDIM * 2;   // 16 MiB
    const size_t fbytes = 1024;                            // 256 flags

    if (ws_size >= xbytes + wbytes + fbytes) {
        unsigned short* xbp = (unsigned short*)d_ws;
        unsigned short* wbp = (unsigned short*)((char*)d_ws + xbytes);
        int*            flg = (int*)((char*)d_ws + xbytes + wbytes);
        conv_pre<<<513, 256, 0, stream>>>(x, lang_ids, W, xbp, wbp, flg);
        mapper_gemm8p<<<256, 640, 0, stream>>>(x, xbp, lang_ids, wbp, bias, flg, out);
    } else {
        mapper_fused<<<TBZ * 16 * 8, 256, 0, stream>>>(x, lang_ids, W, bias, out);
    }
}

// Round 17
// 261.664 us; speedup vs baseline: 3.6220x; 3.6220x over previous
//
#include <hip/hip_runtime.h>
#include <hip/hip_bf16.h>

#define TSEQ 2048
#define TBZ  32
#define TDIM 1024
#define NLS  8

typedef __attribute__((ext_vector_type(8))) short bf16x8;
typedef __attribute__((ext_vector_type(4))) float f32x4;

__device__ inline unsigned int pk2(float lo, float hi) {
    __hip_bfloat162 h = __float22bfloat162_rn(make_float2(lo, hi)); // v_cvt_pk_bf16_f32
    return *reinterpret_cast<const unsigned int*>(&h);
}

__device__ inline void gload_lds16(const void* g, void* l) {
    __builtin_amdgcn_global_load_lds(
        (const __attribute__((address_space(1))) unsigned int*)g,
        (__attribute__((address_space(3))) unsigned int*)l,
        16, 0, 0);
}

// ---------- pass 1: merged conversion, one dispatch, block-uniform roles ----
__global__ __launch_bounds__(256) void conv_all(
    const float* __restrict__ x, const int* __restrict__ lang_ids,
    const float* __restrict__ W,
    unsigned short* __restrict__ xb, unsigned short* __restrict__ wb,
    float* __restrict__ out)
{
    const int bid = blockIdx.x;
    if (bid < 256) {                               // W part: 1M chunks of 8
        const int total = NLS * TDIM * TDIM / 8;
        for (int i = bid * 256 + threadIdx.x; i < total; i += 256 * 256) {
            const float* src = W + (long)i * 8;
            f32x4 v0 = *(const f32x4*)(src);
            f32x4 v1 = *(const f32x4*)(src + 4);
            uint4 o;
            o.x = pk2(v0.x, v0.y); o.y = pk2(v0.z, v0.w);
            o.z = pk2(v1.x, v1.y); o.w = pk2(v1.z, v1.w);
            *(uint4*)(wb + (long)i * 8) = o;
        }
        return;
    }
    // x part: 2048 blocks = 32 b x 64 s-chunks of 32 rows, block-uniform b
    const int xb_id = bid - 256;
    const int b     = xb_id >> 6;
    const int s0c   = (xb_id & 63) * 32;
    const int gid   = 8 - lang_ids[b];
    const bool active = (gid >= 1) && (gid <= 8);

    for (int i = threadIdx.x; i < 32 * 128; i += 256) {
        const int ls = i >> 7;
        const int d8 = i & 127;
        const int s  = s0c + ls;
        const float* src = x + ((long)s * TBZ + b) * TDIM + d8 * 8;
        f32x4 v0 = *(const f32x4*)(src);
        f32x4 v1 = *(const f32x4*)(src + 4);
        if (active) {
            uint4 o;
            o.x = pk2(v0.x, v0.y); o.y = pk2(v0.z, v0.w);
            o.z = pk2(v1.x, v1.y); o.w = pk2(v1.z, v1.w);
            *(uint4*)(xb + ((long)b * TSEQ + s) * TDIM + d8 * 8) = o;
        } else {
            float* dst = out + ((long)s * TBZ + b) * TDIM + d8 * 8;
            *(f32x4*)(dst)     = v0;
            *(f32x4*)(dst + 4) = v1;
        }
    }
}

// ---------- pass 2: persistent 256x256 8-phase bf16 GEMM, 4 m-tiles/block ----
// Final verified configuration (r10/r15: GEMM 158 us, total 259.5, 7x pass).
// 8-phase schedule, both-sides XOR swizzle (0 bank conflicts), counted
// VMC(6) (never 0 in loop), bridge prefetch across m-tiles, C^T epilogue
// with dwordx4 stores, rolled loops, sched_barrier(0) phase pins.
// Measured structural limits (why this is the plateau for this structure):
//  * per-iter 11.9k cy = LDS-drain + MFMA + barriers SERIAL; overlap needs
//    double-buffered fragment regs -> 320 regs/wave > 256 budget at
//    2 waves/SIMD (pool 512/lane/SIMD, m69). 6 schedule probes null/regr.
//  * conv/GEMM overlap: blocked by in-order per-wave vmcnt (r14: +135 us)
//    and by register pool for extra converter waves (r16: acc spilled,
//    VGPR 128->84, WRITE_SIZE 1.5 GB, 6x slowdown).

#define BAR __builtin_amdgcn_s_barrier()
#define SB0 __builtin_amdgcn_sched_barrier(0)
#define VMC(n) asm volatile("s_waitcnt vmcnt(" #n ")" ::: "memory")
#define KAo(kv) (((kv) & 1023) + (((kv) >> 10) << 18))
#define KBo(kv) ((kv) & 1023)

__global__ __launch_bounds__(512, 2) void mapper_gemm8p(
    const unsigned short* __restrict__ xb,      // [b][s][d] bf16
    const int* __restrict__ lang_ids,
    const unsigned short* __restrict__ wb,      // [e][out][in] bf16
    const float* __restrict__ bias,
    float* __restrict__ out)
{
    // XCD-chunked bijective swizzle: 256 = 8 * 32; nt fastest so the 4
    // blocks sharing an A strip-panel are consecutive on one XCD.
    const int p  = blockIdx.x;
    const int l  = (p & 7) * 32 + (p >> 3);
    const int b  = l >> 3;
    const int strip = (l >> 2) & 1;             // 4 m-tiles per strip
    const int nt = l & 3;
    const int s0 = strip * 1024;
    const int e0 = nt * 256;
    const int tid = threadIdx.x;

    const int gid = 8 - lang_ids[b];
    if (!(gid >= 1 && gid <= 8)) return;        // conv_all wrote passthrough
    const int eb = gid - 1;

    __shared__ uint4 ldsbuf[131072 / 16];
    char* ldsc = (char*)ldsbuf;

    const int lane = tid & 63;
    const int wave = tid >> 6;
    const int wr   = wave >> 2;
    const int wc   = wave & 3;
    const int fr   = lane & 15;
    const int fq   = lane >> 4;
    const int fr7  = fr & 7;

    const unsigned short* __restrict__ Aab = xb + (long)b  * TSEQ * TDIM + (long)s0 * TDIM;
    const unsigned short* __restrict__ Bbb = wb + (long)eb * TDIM * TDIM + (long)e0 * TDIM;

    const int L    = lane;
    const int lch8 = ((L & 7) ^ (L >> 3)) * 8;   // pre-inverse-swizzled global chunk
    const int ldA0 = wave * 2048 + L * 16;
    const unsigned short* aG[2][2];
    const unsigned short* bG[2][2];
    #pragma unroll
    for (int j = 0; j < 2; ++j) {
        const int rr = wave * 16 + j * 8 + (L >> 3);
        #pragma unroll
        for (int mh = 0; mh < 2; ++mh)
            aG[j][mh] = Aab + ((rr >> 6) * 128 + mh * 64 + (rr & 63)) * TDIM + lch8;
        #pragma unroll
        for (int nh = 0; nh < 2; ++nh)
            bG[j][nh] = Bbb + ((rr >> 5) * 64 + nh * 32 + (rr & 31)) * TDIM + lch8;
    }

#define STAGE_A(slot, mh, kofs) do { \
    gload_lds16(aG[0][mh] + (kofs), ldsc + (slot)*32768 + (mh)*16384 + ldA0); \
    gload_lds16(aG[1][mh] + (kofs), ldsc + (slot)*32768 + (mh)*16384 + ldA0 + 1024); \
} while (0)
#define STAGE_B(slot, nh, kofs) do { \
    gload_lds16(bG[0][nh] + (kofs), ldsc + 65536 + (slot)*32768 + (nh)*16384 + ldA0); \
    gload_lds16(bG[1][nh] + (kofs), ldsc + 65536 + (slot)*32768 + (nh)*16384 + ldA0 + 1024); \
} while (0)
#define RD_A(slot, mh) do { \
    _Pragma("unroll") for (int ml = 0; ml < 4; ++ml) { \
        const int rr = wr * 64 + ml * 16 + fr; \
        _Pragma("unroll") for (int kk = 0; kk < 2; ++kk) \
            af[ml][kk] = *(const bf16x8*)(ldsc + (slot)*32768 + (mh)*16384 + rr*128 + (((kk*4+fq) ^ fr7) << 4)); \
    } } while (0)
#define RD_B(slot, nh, br) do { \
    _Pragma("unroll") for (int nl = 0; nl < 2; ++nl) { \
        const int rr = wc * 32 + nl * 16 + fr; \
        _Pragma("unroll") for (int kk = 0; kk < 2; ++kk) \
            br[nl][kk] = *(const bf16x8*)(ldsc + 65536 + (slot)*32768 + (nh)*16384 + rr*128 + (((kk*4+fq) ^ fr7) << 4)); \
    } } while (0)
// Swapped operands (C^T): col=lane&15 -> s_local, row=(lane>>4)*4+j -> e_local.
#define MM(mh, nh, br) do { \
    __builtin_amdgcn_s_setprio(1); \
    _Pragma("unroll") for (int ml = 0; ml < 4; ++ml) \
    _Pragma("unroll") for (int nl = 0; nl < 2; ++nl) \
    _Pragma("unroll") for (int kk = 0; kk < 2; ++kk) \
        acc[(mh)*4+ml][(nh)*2+nl] = __builtin_amdgcn_mfma_f32_16x16x32_bf16( \
            br[nl][kk], af[ml][kk], acc[(mh)*4+ml][(nh)*2+nl], 0, 0, 0); \
    __builtin_amdgcn_s_setprio(0); \
} while (0)

    f32x4 acc[8][4];
    #pragma unroll
    for (int m = 0; m < 8; ++m)
        #pragma unroll
        for (int n = 0; n < 4; ++n)
            acc[m][n] = (f32x4){0.f, 0.f, 0.f, 0.f};

    bf16x8 af[4][2], bf0[2][2], bf1[2][2];

    // prologue: tile0 all 4 halves + tile1 {Amh0,Bnh0,Bnh1}
    STAGE_A(0, 0, 0);  STAGE_B(0, 0, 0);  STAGE_B(0, 1, 0);  STAGE_A(0, 1, 0);
    STAGE_A(1, 0, 64); STAGE_B(1, 0, 64); STAGE_B(1, 1, 64);
    VMC(6); BAR; SB0;

    const int cs  = lane & 15;          // s_local
    const int eqb = (lane >> 4) << 2;   // e_local base (4 consecutive)

    #pragma unroll 1
    for (int mtl = 0; mtl < 4; ++mtl) {
        #pragma unroll 1
        for (int it = 0; it < 8; ++it) {
            const int kva = mtl * 1024 + it * 128;
            const int kb = kva + 64;
            const int kn = kva + 128;   // wraps into next m-tile after it=7
            const int km = kva + 192;
            // P1
            RD_A(0, 0); RD_B(0, 0, bf0); STAGE_A(1, 1, KAo(kb));
            BAR; SB0; MM(0, 0, bf0); BAR; SB0;
            // P2
            RD_B(0, 1, bf1); STAGE_A(0, 0, KAo(kn));
            BAR; SB0; MM(0, 1, bf1); BAR; SB0;
            // P3
            RD_A(0, 1); STAGE_B(0, 0, KBo(kn));
            BAR; SB0; MM(1, 0, bf0); BAR; SB0;
            // P4
            STAGE_B(0, 1, KBo(kn));
            BAR; SB0; MM(1, 1, bf1); VMC(6); BAR; SB0;
            // P5
            RD_A(1, 0); RD_B(1, 0, bf0); STAGE_A(0, 1, KAo(kn));
            BAR; SB0; MM(0, 0, bf0); BAR; SB0;
            // P6
            RD_B(1, 1, bf1); STAGE_A(1, 0, KAo(km));
            BAR; SB0; MM(0, 1, bf1); BAR; SB0;
            // P7
            RD_A(1, 1); STAGE_B(1, 0, KBo(km));
            BAR; SB0; MM(1, 0, bf0); BAR; SB0;
            // P8
            STAGE_B(1, 1, KBo(km));
            BAR; SB0; MM(1, 1, bf1); VMC(6); BAR; SB0;
        }

        // epilogue: 32 dwordx4 stores; drain overlaps the bridge prefetch
        const int sb = s0 + mtl * 256 + wr * 128;
        #pragma unroll
        for (int n = 0; n < 4; ++n) {
            const int e = e0 + wc * 64 + n * 16 + eqb;
            const f32x4 bv4 = *(const f32x4*)&bias[eb * TDIM + e];
            #pragma unroll
            for (int m = 0; m < 8; ++m) {
                const int s = sb + m * 16 + cs;
                *(f32x4*)&out[(long)s * (TBZ * TDIM) + b * TDIM + e] = acc[m][n] + bv4;
            }
        }
        #pragma unroll
        for (int m = 0; m < 8; ++m)
            #pragma unroll
            for (int n = 0; n < 4; ++n)
                acc[m][n] = (f32x4){0.f, 0.f, 0.f, 0.f};
    }
#undef STAGE_A
#undef STAGE_B
#undef RD_A
#undef RD_B
#undef MM
}

// ---------- fallback: round-1 fused kernel ----------
__device__ inline unsigned short f2bf(float f) {
    union { float f; unsigned int u; } v; v.f = f;
    unsigned int r = v.u + 0x7fffu + ((v.u >> 16) & 1u);
    return (unsigned short)(r >> 16);
}
constexpr int FLDS = 40;

__global__ __launch_bounds__(256) void mapper_fused(
    const float* __restrict__ x, const int* __restrict__ lang_ids,
    const float* __restrict__ W, const float* __restrict__ bias,
    float* __restrict__ out)
{
    const int bid = blockIdx.x;
    const int b   = bid >> 7;
    const int t   = bid & 127;
    const int mt  = t >> 3;
    const int nt  = t & 7;
    const int s0  = mt * 128;
    const int e0  = nt * 128;
    const int tid = threadIdx.x;

    const int gid = 8 - lang_ids[b];
    const bool active = (gid >= 1) && (gid <= 8);
    int eb = gid - 1; eb = eb < 0 ? 0 : (eb > 7 ? 7 : eb);

    if (!active) {
        const f32x4* xs = (const f32x4*)x;
        f32x4*       os = (f32x4*)out;
        const int rs4 = TBZ * TDIM / 4;
        for (int i = tid; i < 128 * 128 / 4; i += 256) {
            int r = i >> 5, c = i & 31;
            long idx = (long)(s0 + r) * rs4 + b * (TDIM / 4) + (e0 >> 2) + c;
            os[idx] = xs[idx];
        }
        return;
    }

    __shared__ unsigned short As[128 * FLDS];
    __shared__ unsigned short Bs[128 * FLDS];
    const float* __restrict__ Wb = W + (long)eb * TDIM * TDIM;

    const int lane = tid & 63;
    const int wave = tid >> 6;
    const int wrr  = wave >> 1;
    const int wcc  = wave & 1;

    f32x4 acc[4][4];
    #pragma unroll
    for (int m = 0; m < 4; ++m)
        #pragma unroll
        for (int n = 0; n < 4; ++n)
            acc[m][n] = (f32x4){0.f, 0.f, 0.f, 0.f};

    const int rg = tid >> 3;
    const int cg = tid & 7;
    const int fr = lane & 15;
    const int fo = (lane >> 4) * 8;

    for (int k0 = 0; k0 < TDIM; k0 += 32) {
        __syncthreads();
        #pragma unroll
        for (int pp = 0; pp < 4; ++pp) {
            const int r = rg + pp * 32;
            f32x4 av = *(const f32x4*)(x  + (long)(s0 + r) * (TBZ * TDIM) + b * TDIM + k0 + cg * 4);
            f32x4 bv = *(const f32x4*)(Wb + (long)(e0 + r) * TDIM + k0 + cg * 4);
            unsigned int alo = (unsigned)f2bf(av.x) | ((unsigned)f2bf(av.y) << 16);
            unsigned int ahi = (unsigned)f2bf(av.z) | ((unsigned)f2bf(av.w) << 16);
            unsigned int blo = (unsigned)f2bf(bv.x) | ((unsigned)f2bf(bv.y) << 16);
            unsigned int bhi = (unsigned)f2bf(bv.z) | ((unsigned)f2bf(bv.w) << 16);
            *(uint2*)&As[r * FLDS + cg * 4] = make_uint2(alo, ahi);
            *(uint2*)&Bs[r * FLDS + cg * 4] = make_uint2(blo, bhi);
        }
        __syncthreads();

        bf16x8 af2[4], bfm[4];
        #pragma unroll
        for (int m = 0; m < 4; ++m)
            af2[m] = *(const bf16x8*)&As[(wrr * 64 + m * 16 + fr) * FLDS + fo];
        #pragma unroll
        for (int n = 0; n < 4; ++n)
            bfm[n] = *(const bf16x8*)&Bs[(wcc * 64 + n * 16 + fr) * FLDS + fo];
        #pragma unroll
        for (int m = 0; m < 4; ++m)
            #pragma unroll
            for (int n = 0; n < 4; ++n)
                acc[m][n] = __builtin_amdgcn_mfma_f32_16x16x32_bf16(af2[m], bfm[n], acc[m][n], 0, 0, 0);
    }

    const int cr = lane >> 4;
    const int cc2 = lane & 15;
    #pragma unroll
    for (int n = 0; n < 4; ++n) {
        const int e  = e0 + wcc * 64 + n * 16 + cc2;
        const float bv = bias[eb * TDIM + e];
        #pragma unroll
        for (int m = 0; m < 4; ++m) {
            #pragma unroll
            for (int j = 0; j < 4; ++j) {
                const int s = s0 + wrr * 64 + m * 16 + cr * 4 + j;
                out[(long)s * (TBZ * TDIM) + b * TDIM + e] = acc[m][n][j] + bv;
            }
        }
    }
}

extern "C" void kernel_launch(void* const* d_in, const int* in_sizes, int n_in,
                              void* d_out, int out_size, void* d_ws, size_t ws_size,
                              hipStream_t stream) {
    const float* x        = (const float*)d_in[0];
    const int*   lang_ids = (const int*)d_in[1];
    const float* W        = (const float*)d_in[2];
    const float* bias     = (const float*)d_in[3];
    float*       out      = (float*)d_out;

    const size_t xbytes = (size_t)TSEQ * TBZ * TDIM * 2;   // 128 MiB
    const size_t wbytes = (size_t)NLS * TDIM * TDIM * 2;   // 16 MiB

    if (ws_size >= xbytes + wbytes) {
        unsigned short* xbp = (unsigned short*)d_ws;
        unsigned short* wbp = (unsigned short*)((char*)d_ws + xbytes);
        conv_all<<<2304, 256, 0, stream>>>(x, lang_ids, W, xbp, wbp, out);
        mapper_gemm8p<<<256, 512, 0, stream>>>(xbp, lang_ids, wbp, bias, out);
    } else {
        mapper_fused<<<TBZ * 16 * 8, 256, 0, stream>>>(x, lang_ids, W, bias, out);
    }
}